// Round 1
// baseline (11676.477 us; speedup 1.0000x reference)
//
#include <hip/hip_runtime.h>
#include <stdint.h>

#define B_ 256
#define S_ 512
#define H_ 512

// LDS: 144 weight columns (128 gate cols + W_imp col + 15 zero cols) x 520 bf16 (pad 8)
#define WCOLS 144
#define WSTRIDE 520
#define LDS_BYTES (WCOLS * WSTRIDE * 2 + 32 * 4)

typedef __attribute__((ext_vector_type(4))) float f32x4;
typedef __attribute__((ext_vector_type(4))) int   i32x4;
typedef __attribute__((ext_vector_type(8))) short s16x8;

__device__ __forceinline__ short f2bf(float f) {
    union { float f; uint32_t u; } c; c.f = f;
    uint32_t u = c.u;
    u += 0x7fffu + ((u >> 16) & 1u);   // round-to-nearest-even
    return (short)(u >> 16);
}
__device__ __forceinline__ float sig_(float x)  { return 1.0f / (1.0f + __expf(-x)); }
__device__ __forceinline__ float tanh_(float x) { return 1.0f - 2.0f / (1.0f + __expf(2.0f * x)); }

__global__ void __launch_bounds__(256, 1)
lstm_kernel(const float* __restrict__ values, const float* __restrict__ masks,
            const float* __restrict__ Wih_f, const float* __restrict__ Whh_f,
            const float* __restrict__ bih_f, const float* __restrict__ bhh_f,
            const float* __restrict__ Wih_b, const float* __restrict__ Whh_b,
            const float* __restrict__ bih_b, const float* __restrict__ bhh_b,
            const float* __restrict__ W_imp, const float* __restrict__ b_imp,
            unsigned int* ctrs, short* h_buf, float* hfin)
{
    extern __shared__ short smem[];
    short* W_lds  = smem;                         // [WCOLS][WSTRIDE]
    float* cc_lds = (float*)(smem + WCOLS * WSTRIDE);  // [32]

    const int tid  = threadIdx.x;
    const int lane = tid & 63;
    const int wave = tid >> 6;
    const int mw = wave >> 1;      // M-wave: batch half
    const int nw = wave & 1;       // N-wave: hcol half

    // XCD-swizzled cluster decomposition: same cluster -> same blockIdx%8 (L2 locality heuristic)
    const int bid = blockIdx.x;
    const int xg  = bid & 7;       // batch group 0..7
    const int s_  = bid >> 3;      // 0..31
    const int d   = s_ & 1;        // direction
    const int w   = s_ >> 1;       // wg-in-cluster 0..15 (owns hcols w*32..w*32+31)
    const int cluster = xg * 2 + d;

    const float* Whh = d ? Whh_b : Whh_f;
    const float* Wih = d ? Wih_b : Wih_f;
    const float* bih = d ? bih_b : bih_f;
    const float* bhh = d ? bhh_b : bhh_f;

    // ---- stage weights into LDS as bf16: W_lds[lc][k] = Whh[gatecol(lc)][k] ----
    for (int t = tid; t < WCOLS * 2; t += 256) {
        int lc = t >> 1, k0 = (t & 1) * 256;
        short* dst = &W_lds[lc * WSTRIDE + k0];
        if (lc < 128) {
            int g = lc >> 5, jj = lc & 31;
            const float* src = Whh + (size_t)(g * 512 + w * 32 + jj) * 512 + k0;
            for (int k = 0; k < 256; k += 4) {
                f32x4 v = *(const f32x4*)(src + k);
                dst[k+0] = f2bf(v[0]); dst[k+1] = f2bf(v[1]);
                dst[k+2] = f2bf(v[2]); dst[k+3] = f2bf(v[3]);
            }
        } else if (lc == 128) {
            const float* src = W_imp + k0;
            for (int k = 0; k < 256; k += 4) {
                f32x4 v = *(const f32x4*)(src + k);
                dst[k+0] = f2bf(v[0]); dst[k+1] = f2bf(v[1]);
                dst[k+2] = f2bf(v[2]); dst[k+3] = f2bf(v[3]);
            }
        } else {
            for (int k = 0; k < 256; ++k) dst[k] = 0;
        }
    }

    // per-lane constants
    const int jcol = w * 32 + nw * 16 + (lane & 15);   // owned h-column (0..511)
    float bias[4], wih[4];
    #pragma unroll
    for (int g = 0; g < 4; ++g) {
        int gc = g * 512 + jcol;
        bias[g] = bih[gc] + bhh[gc];
        wih[g]  = Wih[gc];
    }
    const float bimp  = b_imp[0];
    const float start = d ? -128.0f : 128.0f;

    unsigned int* ctr = ctrs + cluster * 64;   // 256 B apart

    // ---- init cell: h0,c0 = lstm_cell(start, 0, 0) ----
    float c_reg[4];
    {
        float pre[4];
        #pragma unroll
        for (int g = 0; g < 4; ++g) pre[g] = start * wih[g] + bias[g];
        float i0 = sig_(pre[0]), g0 = tanh_(pre[2]), o0 = sig_(pre[3]);
        float c0 = i0 * g0;
        float h0 = o0 * tanh_(c0);
        #pragma unroll
        for (int r = 0; r < 4; ++r) c_reg[r] = c0;
        short hb16 = f2bf(h0);
        short* dst = h_buf + d * (B_ * H_);    // buffer p=0
        #pragma unroll
        for (int r = 0; r < 4; ++r) {
            int row = xg * 32 + mw * 16 + (lane >> 4) * 4 + r;
            dst[row * H_ + jcol] = hb16;
        }
    }
    __builtin_amdgcn_fence(__ATOMIC_RELEASE, "agent");
    __syncthreads();
    if (tid == 0) {
        __hip_atomic_fetch_add(ctr, 1u, __ATOMIC_RELAXED, __HIP_MEMORY_SCOPE_AGENT);
        while (__hip_atomic_load(ctr, __ATOMIC_RELAXED, __HIP_MEMORY_SCOPE_AGENT) < 16u)
            __builtin_amdgcn_s_sleep(1);
    }
    __syncthreads();
    __builtin_amdgcn_fence(__ATOMIC_ACQUIRE, "agent");

    // ---- sequential scan ----
    for (int t = 0; t < S_; ++t) {
        const int p = t & 1;
        const short* hb_r = h_buf + p       * (2 * B_ * H_) + d * (B_ * H_);
        short*       hb_w = h_buf + (p ^ 1) * (2 * B_ * H_) + d * (B_ * H_);

        // A fragments: h_prev rows for this M-wave. A[m=lane&15][k=(lane>>4)*8+j]
        i32x4 a_regs[16];
        {
            const int arow = xg * 32 + mw * 16 + (lane & 15);
            const i32x4* ap = (const i32x4*)(hb_r + arow * H_ + (lane >> 4) * 8);
            #pragma unroll
            for (int kb = 0; kb < 16; ++kb) a_regs[kb] = ap[kb * 4];
        }
        // prefetch x,m for the cc computation (only the lanes that need them)
        float xv[4], mv[4];
        if (nw == 0 && (lane & 15) == 0) {
            #pragma unroll
            for (int r = 0; r < 4; ++r) {
                int rabs = xg * 32 + mw * 16 + (lane >> 4) * 4 + r;
                xv[r] = values[rabs * S_ + t];
                mv[r] = masks[rabs * S_ + t];
            }
        }

        f32x4 acc0 = {0,0,0,0}, acc1 = {0,0,0,0}, acc2 = {0,0,0,0}, acc3 = {0,0,0,0};
        f32x4 acc4 = {0,0,0,0};  // imp column
        const int ldsl = nw * 16 + (lane & 15);
        const int koff = (lane >> 4) * 8;
        #pragma unroll
        for (int kb = 0; kb < 16; ++kb) {
            s16x8 a = __builtin_bit_cast(s16x8, a_regs[kb]);
            s16x8 b0 = *(const s16x8*)&W_lds[(0 * 32 + ldsl) * WSTRIDE + kb * 32 + koff];
            s16x8 b1 = *(const s16x8*)&W_lds[(1 * 32 + ldsl) * WSTRIDE + kb * 32 + koff];
            s16x8 b2 = *(const s16x8*)&W_lds[(2 * 32 + ldsl) * WSTRIDE + kb * 32 + koff];
            s16x8 b3 = *(const s16x8*)&W_lds[(3 * 32 + ldsl) * WSTRIDE + kb * 32 + koff];
            acc0 = __builtin_amdgcn_mfma_f32_16x16x32_bf16(a, b0, acc0, 0, 0, 0);
            acc1 = __builtin_amdgcn_mfma_f32_16x16x32_bf16(a, b1, acc1, 0, 0, 0);
            acc2 = __builtin_amdgcn_mfma_f32_16x16x32_bf16(a, b2, acc2, 0, 0, 0);
            acc3 = __builtin_amdgcn_mfma_f32_16x16x32_bf16(a, b3, acc3, 0, 0, 0);
            if (nw == 0) {  // wave-uniform
                s16x8 b4 = *(const s16x8*)&W_lds[(128 + (lane & 15)) * WSTRIDE + kb * 32 + koff];
                acc4 = __builtin_amdgcn_mfma_f32_16x16x32_bf16(a, b4, acc4, 0, 0, 0);
            }
        }

        // cc[b] = (1-m)*x + m*(imp+b_imp); imp sits at col 0 of tile 4 (lanes 0,16,32,48 of nw==0)
        if (nw == 0 && (lane & 15) == 0) {
            #pragma unroll
            for (int r = 0; r < 4; ++r) {
                int rloc = mw * 16 + (lane >> 4) * 4 + r;
                float imp = acc4[r] + bimp;
                cc_lds[rloc] = (1.0f - mv[r]) * xv[r] + mv[r] * imp;
            }
        }
        __syncthreads();

        // elementwise gates -> c,h ; write h_new (bf16) to the other buffer
        #pragma unroll
        for (int r = 0; r < 4; ++r) {
            int rloc = mw * 16 + (lane >> 4) * 4 + r;
            float cc = cc_lds[rloc];
            float pi = acc0[r] + cc * wih[0] + bias[0];
            float pf = acc1[r] + cc * wih[1] + bias[1];
            float pg = acc2[r] + cc * wih[2] + bias[2];
            float po = acc3[r] + cc * wih[3] + bias[3];
            float iv = sig_(pi), fv = sig_(pf), gv = tanh_(pg), ov = sig_(po);
            c_reg[r] = fv * c_reg[r] + iv * gv;
            float hn = ov * tanh_(c_reg[r]);
            int rabs = xg * 32 + rloc;
            hb_w[rabs * H_ + jcol] = f2bf(hn);
            if (t == S_ - 1) hfin[d * (B_ * H_) + rabs * H_ + jcol] = hn;
        }

        // cluster barrier: release -> arrive -> spin -> acquire
        __builtin_amdgcn_fence(__ATOMIC_RELEASE, "agent");
        __syncthreads();
        if (tid == 0) {
            __hip_atomic_fetch_add(ctr, 1u, __ATOMIC_RELAXED, __HIP_MEMORY_SCOPE_AGENT);
            unsigned int tgt = 16u * (unsigned)(t + 2);
            while (__hip_atomic_load(ctr, __ATOMIC_RELAXED, __HIP_MEMORY_SCOPE_AGENT) < tgt)
                __builtin_amdgcn_s_sleep(1);
        }
        __syncthreads();
        __builtin_amdgcn_fence(__ATOMIC_ACQUIRE, "agent");
    }
}

__global__ void __launch_bounds__(256)
epilogue_kernel(const float* __restrict__ values, const float* __restrict__ masks,
                const float* __restrict__ hfin, float* __restrict__ out)
{
    int i = blockIdx.x * 256 + threadIdx.x;          // 0..131071
    float h = hfin[i] + hfin[B_ * H_ + i];           // h_f + h_b
    out[i] = h;                                      // output 0: h (B,H)
    float xv = values[i], mv = masks[i];
    out[B_ * H_ + i] = h * (1.0f - mv) + xv * mv;    // output 1: out (B,S,1)
}

extern "C" void kernel_launch(void* const* d_in, const int* in_sizes, int n_in,
                              void* d_out, int out_size, void* d_ws, size_t ws_size,
                              hipStream_t stream) {
    const float* values = (const float*)d_in[0];
    const float* masks  = (const float*)d_in[1];
    const float* Wih_f  = (const float*)d_in[2];
    const float* Whh_f  = (const float*)d_in[3];
    const float* bih_f  = (const float*)d_in[4];
    const float* bhh_f  = (const float*)d_in[5];
    const float* Wih_b  = (const float*)d_in[6];
    const float* Whh_b  = (const float*)d_in[7];
    const float* bih_b  = (const float*)d_in[8];
    const float* bhh_b  = (const float*)d_in[9];
    const float* W_imp  = (const float*)d_in[10];
    const float* b_imp  = (const float*)d_in[11];

    unsigned int* ctrs = (unsigned int*)d_ws;                          // 16 * 256 B
    short* h_buf = (short*)((char*)d_ws + 8192);                       // 2 bufs x 2 dirs x 256 x 512 bf16 = 1 MB
    float* hfin  = (float*)((char*)d_ws + 8192 + 2 * 2 * B_ * H_ * sizeof(short));  // 1 MB

    hipMemsetAsync(d_ws, 0, 8192, stream);   // zero barrier counters (ws is poisoned each launch)

    hipFuncSetAttribute((const void*)lstm_kernel,
                        hipFuncAttributeMaxDynamicSharedMemorySize, LDS_BYTES);

    void* args[] = {
        (void*)&values, (void*)&masks,
        (void*)&Wih_f, (void*)&Whh_f, (void*)&bih_f, (void*)&bhh_f,
        (void*)&Wih_b, (void*)&Whh_b, (void*)&bih_b, (void*)&bhh_b,
        (void*)&W_imp, (void*)&b_imp,
        (void*)&ctrs, (void*)&h_buf, (void*)&hfin
    };
    hipError_t err = hipLaunchCooperativeKernel((const void*)lstm_kernel,
                                                dim3(256), dim3(256), args,
                                                (unsigned int)LDS_BYTES, stream);
    if (err != hipSuccess) {
        // fallback: plain launch (1 wg/CU, grid == CU count -> co-resident in practice)
        lstm_kernel<<<dim3(256), dim3(256), LDS_BYTES, stream>>>(
            values, masks, Wih_f, Whh_f, bih_f, bhh_f,
            Wih_b, Whh_b, bih_b, bhh_b, W_imp, b_imp, ctrs, h_buf, hfin);
    }

    epilogue_kernel<<<dim3((B_ * H_) / 256), dim3(256), 0, stream>>>(
        values, masks, hfin, (float*)d_out);
}

// Round 2
// 2817.057 us; speedup vs baseline: 4.1449x; 4.1449x over previous
//
#include <hip/hip_runtime.h>
#include <stdint.h>

#define B_ 256
#define S_ 512
#define H_ 512

typedef __attribute__((ext_vector_type(4))) float f32x4;
typedef __attribute__((ext_vector_type(4))) int   i32x4;
typedef __attribute__((ext_vector_type(8))) short s16x8;

__device__ __forceinline__ short f2bf(float f) {
    union { float f; uint32_t u; } c; c.f = f;
    uint32_t u = c.u;
    u += 0x7fffu + ((u >> 16) & 1u);   // round-to-nearest-even
    return (short)(u >> 16);
}
__device__ __forceinline__ float sig_(float x)  { return 1.0f / (1.0f + __expf(-x)); }
__device__ __forceinline__ float tanh_(float x) { return 1.0f - 2.0f / (1.0f + __expf(2.0f * x)); }

// Batched cache-bypass (coherent-at-LLC) loads of the 16 A fragments.
// sc0 sc1 => miss L1/L2, read from Infinity Cache (cross-XCD coherent point).
__device__ __forceinline__ void load_a16(const void* p, i32x4* a) {
    asm volatile(
        "global_load_dwordx4 %0, %16, off sc0 sc1\n\t"
        "global_load_dwordx4 %1, %16, off offset:64 sc0 sc1\n\t"
        "global_load_dwordx4 %2, %16, off offset:128 sc0 sc1\n\t"
        "global_load_dwordx4 %3, %16, off offset:192 sc0 sc1\n\t"
        "global_load_dwordx4 %4, %16, off offset:256 sc0 sc1\n\t"
        "global_load_dwordx4 %5, %16, off offset:320 sc0 sc1\n\t"
        "global_load_dwordx4 %6, %16, off offset:384 sc0 sc1\n\t"
        "global_load_dwordx4 %7, %16, off offset:448 sc0 sc1\n\t"
        "global_load_dwordx4 %8, %16, off offset:512 sc0 sc1\n\t"
        "global_load_dwordx4 %9, %16, off offset:576 sc0 sc1\n\t"
        "global_load_dwordx4 %10, %16, off offset:640 sc0 sc1\n\t"
        "global_load_dwordx4 %11, %16, off offset:704 sc0 sc1\n\t"
        "global_load_dwordx4 %12, %16, off offset:768 sc0 sc1\n\t"
        "global_load_dwordx4 %13, %16, off offset:832 sc0 sc1\n\t"
        "global_load_dwordx4 %14, %16, off offset:896 sc0 sc1\n\t"
        "global_load_dwordx4 %15, %16, off offset:960 sc0 sc1\n\t"
        "s_waitcnt vmcnt(0)"
        : "=v"(a[0]), "=v"(a[1]), "=v"(a[2]), "=v"(a[3]),
          "=v"(a[4]), "=v"(a[5]), "=v"(a[6]), "=v"(a[7]),
          "=v"(a[8]), "=v"(a[9]), "=v"(a[10]), "=v"(a[11]),
          "=v"(a[12]), "=v"(a[13]), "=v"(a[14]), "=v"(a[15])
        : "v"(p)
        : "memory");
}

// Write-through h stores (visible at LLC once vmcnt drains): 4 rows, stride H_*2=1024B.
__device__ __forceinline__ void store_h4(void* p, int h0, int h1, int h2, int h3) {
    asm volatile(
        "global_store_short %4, %0, off sc0 sc1\n\t"
        "global_store_short %4, %1, off offset:1024 sc0 sc1\n\t"
        "global_store_short %4, %2, off offset:2048 sc0 sc1\n\t"
        "global_store_short %4, %3, off offset:3072 sc0 sc1"
        :: "v"(h0), "v"(h1), "v"(h2), "v"(h3), "v"(p)
        : "memory");
}

__global__ void __launch_bounds__(256, 1)
lstm_kernel(const float* __restrict__ values, const float* __restrict__ masks,
            const float* __restrict__ Wih_f, const float* __restrict__ Whh_f,
            const float* __restrict__ bih_f, const float* __restrict__ bhh_f,
            const float* __restrict__ Wih_b, const float* __restrict__ Whh_b,
            const float* __restrict__ bih_b, const float* __restrict__ bhh_b,
            const float* __restrict__ W_imp, const float* __restrict__ b_imp,
            unsigned int* ctrs, short* h_buf, float* hfin)
{
    // LDS: W_imp tile in MFMA-lane-sequential chunks (conflict-free), + cc broadcast
    __shared__ short imp_lds[16 * 64 * 8];   // [kb][koff*16+col] chunks of 8 shorts = 16 KB
    __shared__ float cc_lds[32];

    const int tid  = threadIdx.x;
    const int lane = tid & 63;
    const int wave = tid >> 6;
    const int mw = wave >> 1;      // M-wave: batch half
    const int nw = wave & 1;       // N-wave: hcol half

    const int bid = blockIdx.x;
    const int xg  = bid & 7;       // batch group 0..7 (cluster stays on one XCD slot mod 8)
    const int s_  = bid >> 3;
    const int d   = s_ & 1;        // direction
    const int w   = s_ >> 1;       // wg-in-cluster 0..15 (owns hcols w*32..w*32+31)
    const int cluster = xg * 2 + d;

    const float* Whh = d ? Whh_b : Whh_f;
    const float* Wih = d ? Wih_b : Wih_f;
    const float* bih = d ? bih_b : bih_f;
    const float* bhh = d ? bhh_b : bhh_f;

    const int col16 = lane & 15;
    const int koff4 = lane >> 4;          // 0..3
    const int jcol  = w * 32 + nw * 16 + col16;   // owned h-column

    // ---- stage W_imp tile into LDS (col 0 = W_imp, cols 1..15 = 0) ----
    for (int c = tid; c < 1024; c += 256) {
        int ccol = c & 15, ckoff = (c >> 4) & 3, ckb = c >> 6;
        int k0 = ckb * 32 + ckoff * 8;
        short* dst = &imp_lds[c * 8];
        if (ccol == 0) {
            #pragma unroll
            for (int j = 0; j < 8; ++j) dst[j] = f2bf(W_imp[k0 + j]);
        } else {
            #pragma unroll
            for (int j = 0; j < 8; ++j) dst[j] = 0;
        }
    }

    // ---- stage B fragments (4 gate tiles) into REGISTERS: 256 VGPRs, static over all steps ----
    // B[k][n] = Whh[n][k]; lane holds n = jcol, k = kb*32 + koff4*8 + j
    s16x8 bfr[4][16];
    {
        const float* base = Whh + (size_t)jcol * 512 + koff4 * 8;
        #pragma unroll
        for (int g = 0; g < 4; ++g) {
            const float* src = base + (size_t)g * 512 * 512;
            #pragma unroll
            for (int kb = 0; kb < 16; ++kb) {
                f32x4 v0 = *(const f32x4*)(src + kb * 32);
                f32x4 v1 = *(const f32x4*)(src + kb * 32 + 4);
                s16x8 b;
                b[0] = f2bf(v0[0]); b[1] = f2bf(v0[1]); b[2] = f2bf(v0[2]); b[3] = f2bf(v0[3]);
                b[4] = f2bf(v1[0]); b[5] = f2bf(v1[1]); b[6] = f2bf(v1[2]); b[7] = f2bf(v1[3]);
                bfr[g][kb] = b;
            }
        }
    }

    // per-lane constants
    float bias[4], wih[4];
    #pragma unroll
    for (int g = 0; g < 4; ++g) {
        int gc = g * 512 + jcol;
        bias[g] = bih[gc] + bhh[gc];
        wih[g]  = Wih[gc];
    }
    const float bimp  = b_imp[0];
    const float start = d ? -128.0f : 128.0f;

    unsigned int* ctr = ctrs + cluster * 64;

    const int arow   = xg * 32 + mw * 16 + col16;       // A-fragment row (abs batch)
    const int rowbase = xg * 32 + mw * 16 + koff4 * 4;  // first of this lane's 4 C-rows
    const int imp_off = (koff4 * 16 + col16) * 8;       // lds chunk offset (shorts)

    // ---- init cell ----
    float c_reg[4];
    {
        float pre[4];
        #pragma unroll
        for (int g = 0; g < 4; ++g) pre[g] = start * wih[g] + bias[g];
        float i0 = sig_(pre[0]), g0 = tanh_(pre[2]), o0 = sig_(pre[3]);
        float c0 = i0 * g0;
        float h0 = o0 * tanh_(c0);
        #pragma unroll
        for (int r = 0; r < 4; ++r) c_reg[r] = c0;
        int hb16 = (int)(unsigned short)(unsigned)f2bf(h0);
        short* dst = h_buf + d * (B_ * H_) + (size_t)rowbase * H_ + jcol;  // buffer p=0
        store_h4(dst, hb16, hb16, hb16, hb16);
    }
    asm volatile("s_waitcnt vmcnt(0)" ::: "memory");
    __syncthreads();
    if (tid == 0) {
        __hip_atomic_fetch_add(ctr, 1u, __ATOMIC_RELAXED, __HIP_MEMORY_SCOPE_AGENT);
        while (__hip_atomic_load(ctr, __ATOMIC_RELAXED, __HIP_MEMORY_SCOPE_AGENT) < 16u)
            __builtin_amdgcn_s_sleep(1);
    }
    __syncthreads();

    // ---- sequential scan ----
    for (int t = 0; t < S_; ++t) {
        const int p = t & 1;
        const short* hb_r = h_buf + p       * (2 * B_ * H_) + d * (B_ * H_);
        short*       hb_w = h_buf + (p ^ 1) * (2 * B_ * H_) + d * (B_ * H_);

        // x, m for cc (only lanes that need them; plain cached loads)
        float xv[4], mv[4];
        if (nw == 0 && col16 == 0) {
            #pragma unroll
            for (int r = 0; r < 4; ++r) {
                int rabs = rowbase + r;
                xv[r] = values[rabs * S_ + t];
                mv[r] = masks[rabs * S_ + t];
            }
        }

        // A fragments from LLC (bypass L1/L2)
        i32x4 a_regs[16];
        load_a16(hb_r + (size_t)arow * H_ + koff4 * 8, a_regs);

        f32x4 acc0 = {0,0,0,0}, acc1 = {0,0,0,0}, acc2 = {0,0,0,0}, acc3 = {0,0,0,0};
        f32x4 acc4 = {0,0,0,0};
        #pragma unroll
        for (int kb = 0; kb < 16; ++kb) {
            s16x8 a = __builtin_bit_cast(s16x8, a_regs[kb]);
            acc0 = __builtin_amdgcn_mfma_f32_16x16x32_bf16(a, bfr[0][kb], acc0, 0, 0, 0);
            acc1 = __builtin_amdgcn_mfma_f32_16x16x32_bf16(a, bfr[1][kb], acc1, 0, 0, 0);
            acc2 = __builtin_amdgcn_mfma_f32_16x16x32_bf16(a, bfr[2][kb], acc2, 0, 0, 0);
            acc3 = __builtin_amdgcn_mfma_f32_16x16x32_bf16(a, bfr[3][kb], acc3, 0, 0, 0);
            if (nw == 0) {   // wave-uniform branch
                s16x8 b4 = *(const s16x8*)&imp_lds[kb * 512 + imp_off];
                acc4 = __builtin_amdgcn_mfma_f32_16x16x32_bf16(a, b4, acc4, 0, 0, 0);
            }
        }

        // cc[b] = (1-m)*x + m*(imp+b_imp); imp col 0 lives in lanes 0,16,32,48 of nw==0
        if (nw == 0 && col16 == 0) {
            #pragma unroll
            for (int r = 0; r < 4; ++r) {
                float imp = acc4[r] + bimp;
                cc_lds[mw * 16 + koff4 * 4 + r] = (1.0f - mv[r]) * xv[r] + mv[r] * imp;
            }
        }
        __syncthreads();

        // gates -> c,h ; write h_new write-through
        int hbits[4];
        #pragma unroll
        for (int r = 0; r < 4; ++r) {
            float cc = cc_lds[mw * 16 + koff4 * 4 + r];
            float pi = acc0[r] + cc * wih[0] + bias[0];
            float pf = acc1[r] + cc * wih[1] + bias[1];
            float pg = acc2[r] + cc * wih[2] + bias[2];
            float po = acc3[r] + cc * wih[3] + bias[3];
            float iv = sig_(pi), fv = sig_(pf), gv = tanh_(pg), ov = sig_(po);
            c_reg[r] = fv * c_reg[r] + iv * gv;
            float hn = ov * tanh_(c_reg[r]);
            hbits[r] = (int)(unsigned short)(unsigned)f2bf(hn);
            if (t == S_ - 1) hfin[d * (B_ * H_) + (rowbase + r) * H_ + jcol] = hn;
        }
        store_h4(hb_w + (size_t)rowbase * H_ + jcol, hbits[0], hbits[1], hbits[2], hbits[3]);

        // cluster barrier: drain write-through stores, then bare relaxed atomics (NO fences)
        asm volatile("s_waitcnt vmcnt(0)" ::: "memory");
        __syncthreads();
        if (tid == 0) {
            __hip_atomic_fetch_add(ctr, 1u, __ATOMIC_RELAXED, __HIP_MEMORY_SCOPE_AGENT);
            unsigned int tgt = 16u * (unsigned)(t + 2);
            while (__hip_atomic_load(ctr, __ATOMIC_RELAXED, __HIP_MEMORY_SCOPE_AGENT) < tgt)
                __builtin_amdgcn_s_sleep(1);
        }
        __syncthreads();
    }
}

__global__ void __launch_bounds__(256)
epilogue_kernel(const float* __restrict__ values, const float* __restrict__ masks,
                const float* __restrict__ hfin, float* __restrict__ out)
{
    int i = blockIdx.x * 256 + threadIdx.x;          // 0..131071
    float h = hfin[i] + hfin[B_ * H_ + i];           // h_f + h_b
    out[i] = h;                                      // output 0: h (B,H)
    float xv = values[i], mv = masks[i];
    out[B_ * H_ + i] = h * (1.0f - mv) + xv * mv;    // output 1: out (B,S,1)
}

extern "C" void kernel_launch(void* const* d_in, const int* in_sizes, int n_in,
                              void* d_out, int out_size, void* d_ws, size_t ws_size,
                              hipStream_t stream) {
    const float* values = (const float*)d_in[0];
    const float* masks  = (const float*)d_in[1];
    const float* Wih_f  = (const float*)d_in[2];
    const float* Whh_f  = (const float*)d_in[3];
    const float* bih_f  = (const float*)d_in[4];
    const float* bhh_f  = (const float*)d_in[5];
    const float* Wih_b  = (const float*)d_in[6];
    const float* Whh_b  = (const float*)d_in[7];
    const float* bih_b  = (const float*)d_in[8];
    const float* bhh_b  = (const float*)d_in[9];
    const float* W_imp  = (const float*)d_in[10];
    const float* b_imp  = (const float*)d_in[11];

    unsigned int* ctrs = (unsigned int*)d_ws;                          // 16 clusters * 256 B
    short* h_buf = (short*)((char*)d_ws + 8192);                       // 2 x 2 x 256 x 512 bf16 = 1 MB
    float* hfin  = (float*)((char*)d_ws + 8192 + 2 * 2 * B_ * H_ * sizeof(short));

    hipMemsetAsync(d_ws, 0, 8192, stream);   // zero barrier counters

    void* args[] = {
        (void*)&values, (void*)&masks,
        (void*)&Wih_f, (void*)&Whh_f, (void*)&bih_f, (void*)&bhh_f,
        (void*)&Wih_b, (void*)&Whh_b, (void*)&bih_b, (void*)&bhh_b,
        (void*)&W_imp, (void*)&b_imp,
        (void*)&ctrs, (void*)&h_buf, (void*)&hfin
    };
    hipError_t err = hipLaunchCooperativeKernel((const void*)lstm_kernel,
                                                dim3(256), dim3(256), args, 0, stream);
    if (err != hipSuccess) {
        lstm_kernel<<<dim3(256), dim3(256), 0, stream>>>(
            values, masks, Wih_f, Whh_f, bih_f, bhh_f,
            Wih_b, Whh_b, bih_b, bhh_b, W_imp, b_imp, ctrs, h_buf, hfin);
    }

    epilogue_kernel<<<dim3((B_ * H_) / 256), dim3(256), 0, stream>>>(
        values, masks, hfin, (float*)d_out);
}